// Round 1
// baseline (437.016 us; speedup 1.0000x reference)
//
#include <hip/hip_runtime.h>
#include <hip/hip_bf16.h>

#define NN 16384
#define EE 128

typedef __attribute__((ext_vector_type(8))) short bf16x8;   // 8 bf16 = 4 VGPRs (MFMA A/B frag)
typedef __attribute__((ext_vector_type(4))) float f32x4;    // MFMA C/D frag
typedef __attribute__((ext_vector_type(4))) float f4;

static __device__ inline short f2bf(float f) {
    __hip_bfloat16 h = __float2bfloat16(f);
    return *reinterpret_cast<short*>(&h);
}

// ---------------------------------------------------------------------------
// pack_a: A [16384][128] fp32 -> Apk fragment-packed bf16.
// unit = m16*4 + ks  (m16 in [0,1024), ks in [0,4))
// Apk[unit*64 + lane][j] = bf16( A[m16*16 + (lane&15)][ks*32 + (lane>>4)*8 + j] )
// This is exactly the mfma_f32_16x16x32_bf16 A-operand layout (row = lane%16,
// k = (lane/16)*8 + j), so the GEMM loads one coalesced dwordx4 per fragment.
// ---------------------------------------------------------------------------
__global__ __launch_bounds__(256) void pack_a(const float* __restrict__ A,
                                              bf16x8* __restrict__ out) {
    int lane = threadIdx.x & 63;
    int unit = blockIdx.x * 4 + (threadIdx.x >> 6);   // 0..4095
    int m16 = unit >> 2, ks = unit & 3;
    int row = m16 * 16 + (lane & 15);
    int k0  = ks * 32 + (lane >> 4) * 8;
    const float* src = A + (size_t)row * EE + k0;
    f4 v0 = *reinterpret_cast<const f4*>(src);
    f4 v1 = *reinterpret_cast<const f4*>(src + 4);
    bf16x8 r;
    r[0] = f2bf(v0[0]); r[1] = f2bf(v0[1]); r[2] = f2bf(v0[2]); r[3] = f2bf(v0[3]);
    r[4] = f2bf(v1[0]); r[5] = f2bf(v1[1]); r[6] = f2bf(v1[2]); r[7] = f2bf(v1[3]);
    out[(size_t)unit * 64 + lane] = r;
}

// ---------------------------------------------------------------------------
// pack_b: B [128][16384] fp32, W[128] -> Bpk fragment-packed bf16 of (W[k]*B[k][n]).
// unit = n16*4 + ks
// Bpk[unit*64 + lane][j] = bf16( W[k] * B[k][n16*16 + (lane&15)] ),
//   k = ks*32 + (lane>>4)*8 + j
// This is the mfma B-operand layout (col = lane%16, k = (lane/16)*8 + j).
// ---------------------------------------------------------------------------
__global__ __launch_bounds__(256) void pack_b(const float* __restrict__ B,
                                              const float* __restrict__ W,
                                              bf16x8* __restrict__ out) {
    int lane = threadIdx.x & 63;
    int unit = blockIdx.x * 4 + (threadIdx.x >> 6);   // 0..4095
    int n16 = unit >> 2, ks = unit & 3;
    int n  = n16 * 16 + (lane & 15);
    int k0 = ks * 32 + (lane >> 4) * 8;
    bf16x8 r;
#pragma unroll
    for (int j = 0; j < 8; ++j) {
        int k = k0 + j;
        r[j] = f2bf(W[k] * B[(size_t)k * NN + n]);
    }
    out[(size_t)unit * 64 + lane] = r;
}

// ---------------------------------------------------------------------------
// gemm_pk: C[16384][16384] fp32 = Apk x Bpk. One block = 128x128 tile,
// 4 waves (2x2), each wave 64x64 = 4x4 fragments of 16x16, K handled as
// 4 steps of 32. No LDS, no barriers: fragments load straight from the
// L2-resident packed operands (8 MB total).
// ---------------------------------------------------------------------------
__global__ __launch_bounds__(256, 3) void gemm_pk(const bf16x8* __restrict__ Apk,
                                                  const bf16x8* __restrict__ Bpk,
                                                  float* __restrict__ C) {
    // XCD-aware swizzle: 16384 blocks, 8 XCDs -> each XCD gets a contiguous
    // 2048-block chunk of work ids; chunk mapped to a 32(bm) x 64(bn) supertile
    // so per-XCD working set = 1 MB (A) + 2 MB (B) < 4 MB L2.
    int bid = blockIdx.x;
    int swz = (bid & 7) * 2048 + (bid >> 3);
    int st  = swz >> 11;            // supertile 0..7  (4 rows x 2 cols of supertiles)
    int r   = swz & 2047;
    int bm  = (st >> 1) * 32 + (r & 31);
    int bn  = (st & 1) * 64 + (r >> 5);

    int lane = threadIdx.x & 63;
    int wid  = threadIdx.x >> 6;
    int wr   = wid >> 1, wc = wid & 1;
    int m16_0 = bm * 8 + wr * 4;    // first 16-row fragment index for this wave
    int n16_0 = bn * 8 + wc * 4;

    f32x4 acc[4][4];
#pragma unroll
    for (int m = 0; m < 4; ++m)
#pragma unroll
        for (int n = 0; n < 4; ++n)
            acc[m][n] = (f32x4){0.f, 0.f, 0.f, 0.f};

#pragma unroll
    for (int ks = 0; ks < 4; ++ks) {
        bf16x8 a[4], b[4];
#pragma unroll
        for (int m = 0; m < 4; ++m)
            a[m] = Apk[(size_t)((m16_0 + m) * 4 + ks) * 64 + lane];
#pragma unroll
        for (int n = 0; n < 4; ++n)
            b[n] = Bpk[(size_t)((n16_0 + n) * 4 + ks) * 64 + lane];
#pragma unroll
        for (int m = 0; m < 4; ++m)
#pragma unroll
            for (int n = 0; n < 4; ++n)
                acc[m][n] = __builtin_amdgcn_mfma_f32_16x16x32_bf16(a[m], b[n], acc[m][n], 0, 0, 0);
    }

    // C/D layout: col = lane&15, row = (lane>>4)*4 + reg   [measured m89/m91]
    int row0 = bm * 128 + wr * 64 + ((lane >> 4) << 2);
    int col0 = bn * 128 + wc * 64 + (lane & 15);
#pragma unroll
    for (int m = 0; m < 4; ++m) {
#pragma unroll
        for (int ri = 0; ri < 4; ++ri) {
            size_t rowoff = (size_t)(row0 + m * 16 + ri) * NN;
#pragma unroll
            for (int n = 0; n < 4; ++n)
                __builtin_nontemporal_store(acc[m][n][ri], &C[rowoff + col0 + n * 16]);
        }
    }
}

// ---------------------------------------------------------------------------
// Fallback (only if ws_size < 8 MB): plain fp32, correct but slow.
// ---------------------------------------------------------------------------
__global__ __launch_bounds__(64) void gemm_fb(const float* __restrict__ A,
                                              const float* __restrict__ B,
                                              const float* __restrict__ W,
                                              float* __restrict__ C) {
    int col = blockIdx.x * 64 + threadIdx.x;
    int row = blockIdx.y;
    float s = 0.f;
#pragma unroll 8
    for (int k = 0; k < EE; ++k)
        s = fmaf(A[(size_t)row * EE + k] * W[k], B[(size_t)k * NN + col], s);
    C[(size_t)row * NN + col] = s;
}

extern "C" void kernel_launch(void* const* d_in, const int* in_sizes, int n_in,
                              void* d_out, int out_size, void* d_ws, size_t ws_size,
                              hipStream_t stream) {
    const float* A = (const float*)d_in[0];   // DV2_H        [16384,128]
    const float* B = (const float*)d_in[1];   // invDE_HT_DV2 [128,16384]
    const float* W = (const float*)d_in[2];   // W            [128]
    float* C = (float*)d_out;                 // G            [16384,16384] fp32

    const size_t need = (size_t)2 * 4096 * 64 * sizeof(bf16x8);  // 8 MB
    if (ws_size >= need) {
        bf16x8* Apk = (bf16x8*)d_ws;
        bf16x8* Bpk = Apk + (size_t)4096 * 64;
        pack_a<<<1024, 256, 0, stream>>>(A, Apk);
        pack_b<<<1024, 256, 0, stream>>>(B, W, Bpk);
        gemm_pk<<<16384, 256, 0, stream>>>(Apk, Bpk, C);
    } else {
        dim3 g(NN / 64, NN);
        gemm_fb<<<g, 64, 0, stream>>>(A, B, W, C);
    }
}

// Round 2
// 291.872 us; speedup vs baseline: 1.4973x; 1.4973x over previous
//
#include <hip/hip_runtime.h>
#include <hip/hip_bf16.h>

#define NN 16384
#define EE 128

typedef __attribute__((ext_vector_type(8))) short bf16x8;   // 8 bf16 = 4 VGPRs (MFMA A/B frag)
typedef __attribute__((ext_vector_type(4))) float f32x4;    // MFMA C/D frag
typedef __attribute__((ext_vector_type(4))) float f4;

static __device__ inline short f2bf(float f) {
    __hip_bfloat16 h = __float2bfloat16(f);
    return *reinterpret_cast<short*>(&h);
}

// ---------------------------------------------------------------------------
// pack_a: A [16384][128] fp32 -> Apk fragment-packed bf16 (mfma A layout).
// ---------------------------------------------------------------------------
__global__ __launch_bounds__(256) void pack_a(const float* __restrict__ A,
                                              bf16x8* __restrict__ out) {
    int lane = threadIdx.x & 63;
    int unit = blockIdx.x * 4 + (threadIdx.x >> 6);   // 0..4095
    int m16 = unit >> 2, ks = unit & 3;
    int row = m16 * 16 + (lane & 15);
    int k0  = ks * 32 + (lane >> 4) * 8;
    const float* src = A + (size_t)row * EE + k0;
    f4 v0 = *reinterpret_cast<const f4*>(src);
    f4 v1 = *reinterpret_cast<const f4*>(src + 4);
    bf16x8 r;
    r[0] = f2bf(v0[0]); r[1] = f2bf(v0[1]); r[2] = f2bf(v0[2]); r[3] = f2bf(v0[3]);
    r[4] = f2bf(v1[0]); r[5] = f2bf(v1[1]); r[6] = f2bf(v1[2]); r[7] = f2bf(v1[3]);
    out[(size_t)unit * 64 + lane] = r;
}

// ---------------------------------------------------------------------------
// pack_b: B [128][16384] fp32, W[128] -> Bpk = bf16(W[k]*B[k][n]) (mfma B layout).
// ---------------------------------------------------------------------------
__global__ __launch_bounds__(256) void pack_b(const float* __restrict__ B,
                                              const float* __restrict__ W,
                                              bf16x8* __restrict__ out) {
    int lane = threadIdx.x & 63;
    int unit = blockIdx.x * 4 + (threadIdx.x >> 6);   // 0..4095
    int n16 = unit >> 2, ks = unit & 3;
    int n  = n16 * 16 + (lane & 15);
    int k0 = ks * 32 + (lane >> 4) * 8;
    bf16x8 r;
#pragma unroll
    for (int j = 0; j < 8; ++j) {
        int k = k0 + j;
        r[j] = f2bf(W[k] * B[(size_t)k * NN + n]);
    }
    out[(size_t)unit * 64 + lane] = r;
}

// ---------------------------------------------------------------------------
// gemm_pk: C = Apk x Bpk. One block = 128x128 tile, 4 waves (2x2), each wave
// 64x64 = 4x4 frags of 16x16x32, K = 4 steps of 32. No LDS staging for
// operands (L2/L3-resident packed layout). Epilogue: transpose acc through a
// wave-private 16 KB LDS quarter so stores are float4 full rows.
// ---------------------------------------------------------------------------
__global__ __launch_bounds__(256, 2) void gemm_pk(const bf16x8* __restrict__ Apk,
                                                  const bf16x8* __restrict__ Bpk,
                                                  float* __restrict__ C) {
    // XCD-aware swizzle: 16384 blocks, 8 XCDs; each XCD gets a 32(bm)x64(bn)
    // supertile -> per-XCD operand working set ~3 MB < 4 MB L2.
    int bid = blockIdx.x;
    int swz = (bid & 7) * 2048 + (bid >> 3);
    int st  = swz >> 11;            // supertile 0..7  (4 rows x 2 cols)
    int r   = swz & 2047;
    int bm  = (st >> 1) * 32 + (r & 31);
    int bn  = (st & 1) * 64 + (r >> 5);

    int lane = threadIdx.x & 63;
    int wid  = threadIdx.x >> 6;
    int wr   = wid >> 1, wc = wid & 1;
    int m16_0 = bm * 8 + wr * 4;
    int n16_0 = bn * 8 + wc * 4;

    f32x4 acc[4][4];
#pragma unroll
    for (int m = 0; m < 4; ++m)
#pragma unroll
        for (int n = 0; n < 4; ++n)
            acc[m][n] = (f32x4){0.f, 0.f, 0.f, 0.f};

#pragma unroll
    for (int ks = 0; ks < 4; ++ks) {
        bf16x8 a[4], b[4];
#pragma unroll
        for (int m = 0; m < 4; ++m)
            a[m] = Apk[(size_t)((m16_0 + m) * 4 + ks) * 64 + lane];
#pragma unroll
        for (int n = 0; n < 4; ++n)
            b[n] = Bpk[(size_t)((n16_0 + n) * 4 + ks) * 64 + lane];
#pragma unroll
        for (int m = 0; m < 4; ++m)
#pragma unroll
            for (int n = 0; n < 4; ++n)
                acc[m][n] = __builtin_amdgcn_mfma_f32_16x16x32_bf16(a[m], b[n], acc[m][n], 0, 0, 0);
    }

    // ---- epilogue: transpose through wave-private LDS, store float4 rows ----
    // MFMA C/D frag layout: col = lane&15, row = (lane>>4)*4 + reg  [m89/m91]
    // LDS: logical (row, col) -> physical col' = col ^ (((row>>2)&1)<<4).
    //   write: lane groups (lane>>4) differ by 4 in row -> alternate bank
    //   halves -> 2-way (free). read: uniform 32-bank coverage.
    __shared__ float cst[4 * 64 * 64];          // 64 KB, one 16 KB quarter/wave
    float* wl = cst + wid * (64 * 64);

#pragma unroll
    for (int m = 0; m < 4; ++m) {
        int rbase = m * 16 + ((lane >> 4) << 2);
#pragma unroll
        for (int ri = 0; ri < 4; ++ri) {
            int row = rbase + ri;
            int sw  = ((row >> 2) & 1) << 4;
#pragma unroll
            for (int n = 0; n < 4; ++n)
                wl[row * 64 + ((n * 16 + (lane & 15)) ^ sw)] = acc[m][n][ri];
        }
    }
    // No barrier: each wave reads back only its own quarter.

    int gr0 = bm * 128 + wr * 64;
    int gc0 = bn * 128 + wc * 64 + ((lane & 15) << 2);
#pragma unroll
    for (int r4 = 0; r4 < 16; ++r4) {
        int row = r4 * 4 + (lane >> 4);
        int sw  = (r4 & 1) << 4;                // == ((row>>2)&1)<<4
        f4 v = *reinterpret_cast<const f4*>(&wl[row * 64 + (((lane & 15) << 2) ^ sw)]);
        *reinterpret_cast<f4*>(&C[(size_t)(gr0 + row) * NN + gc0]) = v;
    }
}

// ---------------------------------------------------------------------------
// Fallback (only if ws_size < 8 MB): plain fp32, correct but slow.
// ---------------------------------------------------------------------------
__global__ __launch_bounds__(64) void gemm_fb(const float* __restrict__ A,
                                              const float* __restrict__ B,
                                              const float* __restrict__ W,
                                              float* __restrict__ C) {
    int col = blockIdx.x * 64 + threadIdx.x;
    int row = blockIdx.y;
    float s = 0.f;
#pragma unroll 8
    for (int k = 0; k < EE; ++k)
        s = fmaf(A[(size_t)row * EE + k] * W[k], B[(size_t)k * NN + col], s);
    C[(size_t)row * NN + col] = s;
}

extern "C" void kernel_launch(void* const* d_in, const int* in_sizes, int n_in,
                              void* d_out, int out_size, void* d_ws, size_t ws_size,
                              hipStream_t stream) {
    const float* A = (const float*)d_in[0];   // DV2_H        [16384,128]
    const float* B = (const float*)d_in[1];   // invDE_HT_DV2 [128,16384]
    const float* W = (const float*)d_in[2];   // W            [128]
    float* C = (float*)d_out;                 // G            [16384,16384] fp32

    const size_t need = (size_t)2 * 4096 * 64 * sizeof(bf16x8);  // 8 MB
    if (ws_size >= need) {
        bf16x8* Apk = (bf16x8*)d_ws;
        bf16x8* Bpk = Apk + (size_t)4096 * 64;
        pack_a<<<1024, 256, 0, stream>>>(A, Apk);
        pack_b<<<1024, 256, 0, stream>>>(B, W, Bpk);
        gemm_pk<<<16384, 256, 0, stream>>>(Apk, Bpk, C);
    } else {
        dim3 g(NN / 64, NN);
        gemm_fb<<<g, 64, 0, stream>>>(A, B, W, C);
    }
}

// Round 3
// 265.323 us; speedup vs baseline: 1.6471x; 1.1001x over previous
//
#include <hip/hip_runtime.h>
#include <hip/hip_bf16.h>

#define NN 16384
#define EE 128

typedef __attribute__((ext_vector_type(8))) short bf16x8;   // 8 bf16 = 4 VGPRs (MFMA A/B frag)
typedef __attribute__((ext_vector_type(4))) float f32x4;    // MFMA C/D frag
typedef __attribute__((ext_vector_type(4))) float f4;

static __device__ inline short f2bf(float f) {
    __hip_bfloat16 h = __float2bfloat16(f);
    return *reinterpret_cast<short*>(&h);
}

// ---------------------------------------------------------------------------
// pack_a: A [16384][128] fp32 -> Apk fragment-packed bf16 (mfma A layout).
// ---------------------------------------------------------------------------
__global__ __launch_bounds__(256) void pack_a(const float* __restrict__ A,
                                              bf16x8* __restrict__ out) {
    int lane = threadIdx.x & 63;
    int unit = blockIdx.x * 4 + (threadIdx.x >> 6);   // 0..4095
    int m16 = unit >> 2, ks = unit & 3;
    int row = m16 * 16 + (lane & 15);
    int k0  = ks * 32 + (lane >> 4) * 8;
    const float* src = A + (size_t)row * EE + k0;
    f4 v0 = *reinterpret_cast<const f4*>(src);
    f4 v1 = *reinterpret_cast<const f4*>(src + 4);
    bf16x8 r;
    r[0] = f2bf(v0[0]); r[1] = f2bf(v0[1]); r[2] = f2bf(v0[2]); r[3] = f2bf(v0[3]);
    r[4] = f2bf(v1[0]); r[5] = f2bf(v1[1]); r[6] = f2bf(v1[2]); r[7] = f2bf(v1[3]);
    out[(size_t)unit * 64 + lane] = r;
}

// ---------------------------------------------------------------------------
// pack_b: B [128][16384] fp32, W[128] -> Bpk = bf16(W[k]*B[k][n]) (mfma B layout).
// ---------------------------------------------------------------------------
__global__ __launch_bounds__(256) void pack_b(const float* __restrict__ B,
                                              const float* __restrict__ W,
                                              bf16x8* __restrict__ out) {
    int lane = threadIdx.x & 63;
    int unit = blockIdx.x * 4 + (threadIdx.x >> 6);   // 0..4095
    int n16 = unit >> 2, ks = unit & 3;
    int n  = n16 * 16 + (lane & 15);
    int k0 = ks * 32 + (lane >> 4) * 8;
    bf16x8 r;
#pragma unroll
    for (int j = 0; j < 8; ++j) {
        int k = k0 + j;
        r[j] = f2bf(W[k] * B[(size_t)k * NN + n]);
    }
    out[(size_t)unit * 64 + lane] = r;
}

// ---------------------------------------------------------------------------
// gemm_pk: C = Apk x Bpk. One block = 128x128 tile, 4 waves (2x2), each wave
// 64x64 = 4x4 frags of 16x16x32, K = 4 steps of 32. Operand frags load
// straight from the L2/L3-resident packed layout (no LDS staging).
// Epilogue: chunked transpose — 16 rows (one m-band) at a time through a
// 4 KB wave-private LDS chunk, so block LDS = 16 KB -> 4 blocks/CU
// (vs 2 at R2's 64 KB), doubling waves/SIMD for latency hiding.
// ---------------------------------------------------------------------------
__global__ __launch_bounds__(256, 4) void gemm_pk(const bf16x8* __restrict__ Apk,
                                                  const bf16x8* __restrict__ Bpk,
                                                  float* __restrict__ C) {
    // XCD-aware swizzle: 16384 blocks, 8 XCDs; each XCD gets a 32(bm)x64(bn)
    // supertile -> per-XCD operand working set ~3 MB < 4 MB L2.
    int bid = blockIdx.x;
    int swz = (bid & 7) * 2048 + (bid >> 3);
    int st  = swz >> 11;            // supertile 0..7  (4 rows x 2 cols)
    int r   = swz & 2047;
    int bm  = (st >> 1) * 32 + (r & 31);
    int bn  = (st & 1) * 64 + (r >> 5);

    int lane = threadIdx.x & 63;
    int wid  = threadIdx.x >> 6;
    int wr   = wid >> 1, wc = wid & 1;
    int m16_0 = bm * 8 + wr * 4;
    int n16_0 = bn * 8 + wc * 4;

    f32x4 acc[4][4];
#pragma unroll
    for (int m = 0; m < 4; ++m)
#pragma unroll
        for (int n = 0; n < 4; ++n)
            acc[m][n] = (f32x4){0.f, 0.f, 0.f, 0.f};

#pragma unroll
    for (int ks = 0; ks < 4; ++ks) {
        bf16x8 a[4], b[4];
#pragma unroll
        for (int m = 0; m < 4; ++m)
            a[m] = Apk[(size_t)((m16_0 + m) * 4 + ks) * 64 + lane];
#pragma unroll
        for (int n = 0; n < 4; ++n)
            b[n] = Bpk[(size_t)((n16_0 + n) * 4 + ks) * 64 + lane];
#pragma unroll
        for (int m = 0; m < 4; ++m)
#pragma unroll
            for (int n = 0; n < 4; ++n)
                acc[m][n] = __builtin_amdgcn_mfma_f32_16x16x32_bf16(a[m], b[n], acc[m][n], 0, 0, 0);
    }

    // ---- epilogue: chunked transpose (16 rows / 4 KB per wave at a time) ----
    // MFMA C/D frag layout: col = lane&15, row = (lane>>4)*4 + reg  [m89/m91]
    __shared__ float cst[4 * 16 * 64];          // 16 KB total, 4 KB per wave
    float* wl = cst + wid * (16 * 64);

    int rg  = lane >> 4;                         // lane group 0..3
    int l15 = lane & 15;
    int gr0 = bm * 128 + wr * 64;
    int gc0 = bn * 128 + wc * 64 + (l15 << 2);

#pragma unroll
    for (int m = 0; m < 4; ++m) {
        // write: rows rl = rg*4+ri; swizzle keyed (rl>>2)&1 = rg&1 -> 2-way (free)
        int swW = (rg & 1) << 4;
#pragma unroll
        for (int ri = 0; ri < 4; ++ri) {
            int rl = rg * 4 + ri;
#pragma unroll
            for (int n = 0; n < 4; ++n)
                wl[rl * 64 + ((n * 16 + l15) ^ swW)] = acc[m][n][ri];
        }
        // read back float4 rows; rl = r4*4 + rg, swizzle key (rl>>2)&1 = r4&1
#pragma unroll
        for (int r4 = 0; r4 < 4; ++r4) {
            int rl = r4 * 4 + rg;
            int swR = (r4 & 1) << 4;
            f4 v = *reinterpret_cast<const f4*>(&wl[rl * 64 + (((l15 << 2)) ^ swR)]);
            *reinterpret_cast<f4*>(&C[(size_t)(gr0 + m * 16 + rl) * NN + gc0]) = v;
        }
        // next m reuses the same 4 KB chunk; compiler inserts the lgkmcnt
        // ordering (wave-private chunk, no barrier needed).
    }
}

// ---------------------------------------------------------------------------
// Fallback (only if ws_size < 8 MB): plain fp32, correct but slow.
// ---------------------------------------------------------------------------
__global__ __launch_bounds__(64) void gemm_fb(const float* __restrict__ A,
                                              const float* __restrict__ B,
                                              const float* __restrict__ W,
                                              float* __restrict__ C) {
    int col = blockIdx.x * 64 + threadIdx.x;
    int row = blockIdx.y;
    float s = 0.f;
#pragma unroll 8
    for (int k = 0; k < EE; ++k)
        s = fmaf(A[(size_t)row * EE + k] * W[k], B[(size_t)k * NN + col], s);
    C[(size_t)row * NN + col] = s;
}

extern "C" void kernel_launch(void* const* d_in, const int* in_sizes, int n_in,
                              void* d_out, int out_size, void* d_ws, size_t ws_size,
                              hipStream_t stream) {
    const float* A = (const float*)d_in[0];   // DV2_H        [16384,128]
    const float* B = (const float*)d_in[1];   // invDE_HT_DV2 [128,16384]
    const float* W = (const float*)d_in[2];   // W            [128]
    float* C = (float*)d_out;                 // G            [16384,16384] fp32

    const size_t need = (size_t)2 * 4096 * 64 * sizeof(bf16x8);  // 8 MB
    if (ws_size >= need) {
        bf16x8* Apk = (bf16x8*)d_ws;
        bf16x8* Bpk = Apk + (size_t)4096 * 64;
        pack_a<<<1024, 256, 0, stream>>>(A, Apk);
        pack_b<<<1024, 256, 0, stream>>>(B, W, Bpk);
        gemm_pk<<<16384, 256, 0, stream>>>(Apk, Bpk, C);
    } else {
        dim3 g(NN / 64, NN);
        gemm_fb<<<g, 64, 0, stream>>>(A, B, W, C);
    }
}